// Round 7
// baseline (655.623 us; speedup 1.0000x reference)
//
#include <hip/hip_runtime.h>

#define BB 1024
#define TT 512
#define KK 64

// broadcast lane i's float to all lanes via SGPR (no LDS / DS-pipe traffic)
#define RL(x, i) __int_as_float(__builtin_amdgcn_readlane(__float_as_int(x), (i)))

__global__ void crf_zero_loss(float* out) {
    out[(size_t)BB * TT] = 0.0f;
}

// combine (v,i); ties -> lower index (jnp.argmax first-occurrence)
#define COMB(v, i, v2, i2)                                   \
    { bool _t = ((v2) > (v)) || ((v2) == (v) && (i2) < (i)); \
      (v) = _t ? (v2) : (v); (i) = _t ? (i2) : (i); }

__global__ __launch_bounds__(128, 1)
void crf_fwd_kernel(const float* __restrict__ logits,
                    const int* __restrict__ nwords,
                    const int* __restrict__ tags,
                    const float* __restrict__ trans,
                    float* __restrict__ out) {
    __shared__ unsigned char sBP[TT * KK];        // backpointers
    __shared__ unsigned char sTag[TT];            // backtraced tags staging

    const int b    = blockIdx.x;
    const int lane = threadIdx.x & 63;
    const int wid  = threadIdx.x >> 6;
    const int len  = nwords[b];
    const float* lg = logits + (size_t)b * TT * KK;

    if (wid == 0) {
        // ---------------- Viterbi wave (register broadcast, no LDS reads) ----------------
        float tc[KK];                             // trans[:, lane]
#pragma unroll
        for (int i = 0; i < KK; ++i) tc[i] = trans[i * KK + lane];

        float alpha = lg[lane];                   // t = 0

        for (int t = 1; t < len; ++t) {
            const float logit = lg[t * KK + lane];

            // 4-slot ascending-index scan over i; alpha broadcast via readlane
            float bx = RL(alpha, 0) + tc[0]; int ix = 0;
            float by = RL(alpha, 1) + tc[1]; int iy = 1;
            float bz = RL(alpha, 2) + tc[2]; int iz = 2;
            float bw = RL(alpha, 3) + tc[3]; int iw = 3;
#pragma unroll
            for (int q = 1; q < 16; ++q) {
                float sx = RL(alpha, 4*q+0) + tc[4*q+0]; if (sx > bx) { bx = sx; ix = 4*q+0; }
                float sy = RL(alpha, 4*q+1) + tc[4*q+1]; if (sy > by) { by = sy; iy = 4*q+1; }
                float sz = RL(alpha, 4*q+2) + tc[4*q+2]; if (sz > bz) { bz = sz; iz = 4*q+2; }
                float sw = RL(alpha, 4*q+3) + tc[4*q+3]; if (sw > bw) { bw = sw; iw = 4*q+3; }
            }
            COMB(bx, ix, by, iy); COMB(bx, ix, bz, iz); COMB(bx, ix, bw, iw);

            sBP[t * KK + lane] = (unsigned char)ix;   // only DS op on the step path
            alpha = bx + logit;
        }

        // last = first-occurrence argmax over lanes of alpha
        float v = alpha; int idx = lane;
#pragma unroll
        for (int m = 32; m >= 1; m >>= 1) {
            float ov = __shfl_xor(v, m); int oi = __shfl_xor(idx, m);
            COMB(v, idx, ov, oi);
        }
        const int last = idx;                     // wave-uniform

        // tail: positions len-1 .. T-1 are all `last`
        for (int t = len - 1 + lane; t < TT; t += 64)
            out[(size_t)b * TT + t] = (float)last;

        // backtrace through LDS backpointers (uniform broadcast byte reads)
        int tag = last;
        for (int t = len - 1; t >= 1; --t) {
            tag = sBP[t * KK + tag];
            sTag[t - 1] = (unsigned char)tag;
        }
        for (int t = lane; t < len - 1; t += 64)
            out[(size_t)b * TT + t] = (float)sTag[t];

    } else {
        // ---------------- logsumexp + score wave (register broadcast) ----------------
        float E[KK];                              // exp(trans[:, lane])
#pragma unroll
        for (int i = 0; i < KK; ++i) E[i] = __expf(trans[i * KK + lane]);

        float a = lg[lane];                       // t = 0
        float C = 0.0f;
        int   tprev = tags[b * TT];
        float acc = (lane == tprev) ? a : 0.0f;   // unary for t = 0

        for (int t = 1; t < len; ++t) {
            // wave max of a (same math/order as R1 baseline)
            float M = a;
#pragma unroll
            for (int m = 32; m >= 1; m >>= 1) M = fmaxf(M, __shfl_xor(M, m));
            const float p = __expf(a - M);

            float s0 = 0.f, s1 = 0.f, s2 = 0.f, s3 = 0.f;
#pragma unroll
            for (int q = 0; q < 16; ++q) {
                s0 = fmaf(RL(p, 4*q+0), E[4*q+0], s0);
                s1 = fmaf(RL(p, 4*q+1), E[4*q+1], s1);
                s2 = fmaf(RL(p, 4*q+2), E[4*q+2], s2);
                s3 = fmaf(RL(p, 4*q+3), E[4*q+3], s3);
            }
            const float sum   = (s0 + s1) + (s2 + s3);
            const float logit = lg[t * KK + lane];
            a = __logf(sum) + logit;
            C += M;

            const int tg = tags[b * TT + t];
            if (lane == tg) acc += logit;                    // unary
            if (lane == 0)  acc += trans[tprev * KK + tg];   // binary
            tprev = tg;
        }

        // log_norm = C + logsumexp over lanes of a
        float M = a;
#pragma unroll
        for (int m = 32; m >= 1; m >>= 1) M = fmaxf(M, __shfl_xor(M, m));
        float e = __expf(a - M);
#pragma unroll
        for (int m = 32; m >= 1; m >>= 1) e += __shfl_xor(e, m);
        const float log_norm = C + M + __logf(e);

        // score = lane-sum of acc
#pragma unroll
        for (int m = 32; m >= 1; m >>= 1) acc += __shfl_xor(acc, m);

        if (lane == 0)
            atomicAdd(out + (size_t)BB * TT, (log_norm - acc) * (1.0f / BB));
    }
}

extern "C" void kernel_launch(void* const* d_in, const int* in_sizes, int n_in,
                              void* d_out, int out_size, void* d_ws, size_t ws_size,
                              hipStream_t stream) {
    const float* logits = (const float*)d_in[0];
    const int*   nwords = (const int*)d_in[1];
    const int*   tags   = (const int*)d_in[2];
    const float* trans  = (const float*)d_in[3];
    float*       out    = (float*)d_out;

    crf_zero_loss<<<1, 1, 0, stream>>>(out);
    crf_fwd_kernel<<<BB, 128, 0, stream>>>(logits, nwords, tags, trans, out);
}

// Round 8
// 544.610 us; speedup vs baseline: 1.2038x; 1.2038x over previous
//
#include <hip/hip_runtime.h>

#define BB 1024
#define TT 512
#define KK 64

__global__ void crf_zero_loss(float* out) {
    out[(size_t)BB * TT] = 0.0f;
}

// combine (v,i); ties -> lower index (jnp.argmax first-occurrence)
#define COMB(v, i, v2, i2)                                   \
    { bool _t = ((v2) > (v)) || ((v2) == (v) && (i2) < (i)); \
      (v) = _t ? (v2) : (v); (i) = _t ? (i2) : (i); }

__global__ __launch_bounds__(128, 1)
void crf_fwd_kernel(const float* __restrict__ logits,
                    const int* __restrict__ nwords,
                    const int* __restrict__ tags,
                    const float* __restrict__ trans,
                    float* __restrict__ out) {
    __shared__ __align__(16) float sA[KK];        // viterbi alpha broadcast
    __shared__ __align__(16) float sP[KK];        // lse p broadcast
    __shared__ unsigned char sBP[TT * KK];        // backpointers
    __shared__ unsigned char sTag[TT];            // backtraced tags staging

    const int b    = blockIdx.x;
    const int lane = threadIdx.x & 63;
    const int wid  = threadIdx.x >> 6;
    const int len  = nwords[b];
    const float* lg = logits + (size_t)b * TT * KK;

    if (wid == 0) {
        // ---------------- Viterbi wave (R1 + 2-ahead logits prefetch) ----------------
        float tc[KK];
#pragma unroll
        for (int i = 0; i < KK; ++i) tc[i] = trans[i * KK + lane];

        float alpha = lg[lane];          // t = 0
        sA[lane] = alpha;

        float f1 = lg[(len > 1 ? 1 : 0) * KK + lane];
        float f2 = lg[(len > 2 ? 2 : (len > 1 ? 1 : 0)) * KK + lane];

        for (int t = 1; t < len; ++t) {
            const float logit = f1;      // row t, prefetched 2 iterations ago
            f1 = f2;
            int tn = t + 2; if (tn > len - 1) tn = len - 1;
            f2 = lg[tn * KK + lane];     // issue early; consumed 2 steps later

            float best = -__builtin_inff();
            int   bidx = 0;
#pragma unroll
            for (int q = 0; q < KK / 4; ++q) {
                const float4 a4 = reinterpret_cast<const float4*>(sA)[q];
                { float s = a4.x + tc[4*q+0]; if (s > best) { best = s; bidx = 4*q+0; } }
                { float s = a4.y + tc[4*q+1]; if (s > best) { best = s; bidx = 4*q+1; } }
                { float s = a4.z + tc[4*q+2]; if (s > best) { best = s; bidx = 4*q+2; } }
                { float s = a4.w + tc[4*q+3]; if (s > best) { best = s; bidx = 4*q+3; } }
            }
            alpha = best + logit;
            sBP[t * KK + lane] = (unsigned char)bidx;
            sA[lane] = alpha;            // same-wave LDS ops are in-order
        }

        // last = first-occurrence argmax over lanes of alpha
        float v = alpha;
        int   idx = lane;
#pragma unroll
        for (int m = 32; m >= 1; m >>= 1) {
            const float ov = __shfl_xor(v, m);
            const int   oi = __shfl_xor(idx, m);
            COMB(v, idx, ov, oi);
        }
        const int last = idx;            // wave-uniform

        // tail: positions len-1 .. T-1 are all `last`
        for (int t = len - 1 + lane; t < TT; t += 64)
            out[(size_t)b * TT + t] = (float)last;

        // backtrace through LDS backpointers (uniform broadcast byte reads)
        int tag = last;
        for (int t = len - 1; t >= 1; --t) {
            tag = sBP[t * KK + tag];
            sTag[t - 1] = (unsigned char)tag;
        }
        // coalesced prediction writes for 0 .. len-2
        for (int t = lane; t < len - 1; t += 64)
            out[(size_t)b * TT + t] = (float)sTag[t];

    } else {
        // ---------------- logsumexp + score wave (R1 + 2-ahead prefetch) ----------------
        float E[KK];
#pragma unroll
        for (int i = 0; i < KK; ++i) E[i] = __expf(trans[i * KK + lane]);

        float a = lg[lane];              // t = 0
        float C = 0.0f;
        int   tprev = tags[b * TT];
        float acc = (lane == tprev) ? a : 0.0f;   // unary for t = 0

        float f1 = lg[(len > 1 ? 1 : 0) * KK + lane];
        float f2 = lg[(len > 2 ? 2 : (len > 1 ? 1 : 0)) * KK + lane];
        int  tg1 = tags[b * TT + (len > 1 ? 1 : 0)];
        int  tg2 = tags[b * TT + (len > 2 ? 2 : (len > 1 ? 1 : 0))];

        for (int t = 1; t < len; ++t) {
            const float logit = f1; f1 = f2;
            const int   tg    = tg1; tg1 = tg2;
            int tn = t + 2; if (tn > len - 1) tn = len - 1;
            f2  = lg[tn * KK + lane];
            tg2 = tags[b * TT + tn];

            // wave max of a (same math/order as R1)
            float M = a;
#pragma unroll
            for (int m = 32; m >= 1; m >>= 1) M = fmaxf(M, __shfl_xor(M, m));
            const float p = __expf(a - M);
            sP[lane] = p;

            float s0 = 0.f, s1 = 0.f, s2 = 0.f, s3 = 0.f;
#pragma unroll
            for (int q = 0; q < KK / 4; ++q) {
                const float4 p4 = reinterpret_cast<const float4*>(sP)[q];
                s0 = fmaf(p4.x, E[4*q+0], s0);
                s1 = fmaf(p4.y, E[4*q+1], s1);
                s2 = fmaf(p4.z, E[4*q+2], s2);
                s3 = fmaf(p4.w, E[4*q+3], s3);
            }
            const float sum = (s0 + s1) + (s2 + s3);
            a = __logf(sum) + logit;
            C += M;

            if (lane == tg) acc += logit;                    // unary
            if (lane == 0)  acc += trans[tprev * KK + tg];   // binary
            tprev = tg;
        }

        // log_norm = C + logsumexp over lanes of a
        float M = a;
#pragma unroll
        for (int m = 32; m >= 1; m >>= 1) M = fmaxf(M, __shfl_xor(M, m));
        float e = __expf(a - M);
#pragma unroll
        for (int m = 32; m >= 1; m >>= 1) e += __shfl_xor(e, m);
        const float log_norm = C + M + __logf(e);

        // score = lane-sum of acc
#pragma unroll
        for (int m = 32; m >= 1; m >>= 1) acc += __shfl_xor(acc, m);

        if (lane == 0)
            atomicAdd(out + (size_t)BB * TT, (log_norm - acc) * (1.0f / BB));
    }
}

extern "C" void kernel_launch(void* const* d_in, const int* in_sizes, int n_in,
                              void* d_out, int out_size, void* d_ws, size_t ws_size,
                              hipStream_t stream) {
    const float* logits = (const float*)d_in[0];
    const int*   nwords = (const int*)d_in[1];
    const int*   tags   = (const int*)d_in[2];
    const float* trans  = (const float*)d_in[3];
    float*       out    = (float*)d_out;

    crf_zero_loss<<<1, 1, 0, stream>>>(out);
    crf_fwd_kernel<<<BB, 128, 0, stream>>>(logits, nwords, tags, trans, out);
}

// Round 9
// 508.454 us; speedup vs baseline: 1.2894x; 1.0711x over previous
//
#include <hip/hip_runtime.h>

#define BB 1024
#define TT 512
#define KK 64

__global__ void crf_zero_loss(float* out) {
    out[(size_t)BB * TT] = 0.0f;
}

// combine (v,i); ties -> lower index (jnp.argmax first-occurrence)
#define COMB(v, i, v2, i2)                                   \
    { bool _t = ((v2) > (v)) || ((v2) == (v) && (i2) < (i)); \
      (v) = _t ? (v2) : (v); (i) = _t ? (i2) : (i); }

__global__ __launch_bounds__(128, 1)
void crf_fwd_kernel(const float* __restrict__ logits,
                    const int* __restrict__ nwords,
                    const int* __restrict__ tags,
                    const float* __restrict__ trans,
                    float* __restrict__ out) {
    __shared__ __align__(16) float sA[KK];        // viterbi alpha broadcast
    __shared__ __align__(16) float sU[KK];        // exp-domain lse state broadcast
    __shared__ unsigned char sBP[TT * KK];        // backpointers
    __shared__ unsigned char sTag[TT];            // backtraced tags staging

    const int b    = blockIdx.x;
    const int lane = threadIdx.x & 63;
    const int wid  = threadIdx.x >> 6;
    const int len  = nwords[b];
    const float* lg = logits + (size_t)b * TT * KK;

    if (wid == 0) {
        // ---------------- Viterbi wave (byte-identical to R1 baseline) ----------------
        float tc[KK];
#pragma unroll
        for (int i = 0; i < KK; ++i) tc[i] = trans[i * KK + lane];

        float alpha = lg[lane];          // t = 0
        sA[lane] = alpha;

        for (int t = 1; t < len; ++t) {
            float best = -__builtin_inff();
            int   bidx = 0;
#pragma unroll
            for (int q = 0; q < KK / 4; ++q) {
                const float4 a4 = reinterpret_cast<const float4*>(sA)[q];
                { float s = a4.x + tc[4*q+0]; if (s > best) { best = s; bidx = 4*q+0; } }
                { float s = a4.y + tc[4*q+1]; if (s > best) { best = s; bidx = 4*q+1; } }
                { float s = a4.z + tc[4*q+2]; if (s > best) { best = s; bidx = 4*q+2; } }
                { float s = a4.w + tc[4*q+3]; if (s > best) { best = s; bidx = 4*q+3; } }
            }
            const float logit = lg[t * KK + lane];
            alpha = best + logit;
            sBP[t * KK + lane] = (unsigned char)bidx;
            sA[lane] = alpha;            // same-wave LDS ops are in-order
        }

        // last = first-occurrence argmax over lanes of alpha
        float v = alpha;
        int   idx = lane;
#pragma unroll
        for (int m = 32; m >= 1; m >>= 1) {
            const float ov = __shfl_xor(v, m);
            const int   oi = __shfl_xor(idx, m);
            COMB(v, idx, ov, oi);
        }
        const int last = idx;            // wave-uniform

        // tail: positions len-1 .. T-1 are all `last`
        for (int t = len - 1 + lane; t < TT; t += 64)
            out[(size_t)b * TT + t] = (float)last;

        // backtrace through LDS backpointers (uniform broadcast byte reads)
        int tag = last;
        for (int t = len - 1; t >= 1; --t) {
            tag = sBP[t * KK + tag];
            sTag[t - 1] = (unsigned char)tag;
        }
        // coalesced prediction writes for 0 .. len-2
        for (int t = lane; t < len - 1; t += 64)
            out[(size_t)b * TT + t] = (float)sTag[t];

    } else {
        // ---------------- exp-domain LSE wave + hoisted score ----------------
        // (exp-domain recurrence numerics identical to R3, which passed absmax 0.0)
        float E[KK];                     // exp(trans[:, lane])
#pragma unroll
        for (int i = 0; i < KK; ++i) E[i] = __expf(trans[i * KK + lane]);

        // ---- sequence score: fully parallel over t (off the recurrence) ----
        const int bT = b * TT;
        float sc = 0.0f;
        for (int t = lane; t < len; t += 64) {
            const int tg = tags[bT + t];
            sc += lg[t * KK + tg];                              // unary
            if (t + 1 < len) sc += trans[tg * KK + tags[bT + t + 1]];  // binary
        }
#pragma unroll
        for (int m = 32; m >= 1; m >>= 1) sc += __shfl_xor(sc, m);
        // sc now wave-uniform = full sequence score

        // ---- exp-domain forward recurrence ----
        const float lg0 = lg[lane];
        float M = lg0;
#pragma unroll
        for (int m = 32; m >= 1; m >>= 1) M = fmaxf(M, __shfl_xor(M, m));
        float C = M;                     // accumulated log-offset (wave-uniform)
        float u = __expf(lg0 - M);       // u[lane] = exp(alpha[lane] - C)
        sU[lane] = u;

        for (int t = 1; t < len; ++t) {
            const float logit = lg[t * KK + lane];

            float s0 = 0.f, s1 = 0.f, s2 = 0.f, s3 = 0.f;
#pragma unroll
            for (int q = 0; q < KK / 4; ++q) {
                const float4 u4 = reinterpret_cast<const float4*>(sU)[q];
                s0 = fmaf(u4.x, E[4*q+0], s0);
                s1 = fmaf(u4.y, E[4*q+1], s1);
                s2 = fmaf(u4.z, E[4*q+2], s2);
                s3 = fmaf(u4.w, E[4*q+3], s3);
            }
            u = ((s0 + s1) + (s2 + s3)) * __expf(logit);

            if ((t & 7) == 0) {          // deferred rescale (overflow-safe within 8 steps)
                float mx = u;
#pragma unroll
                for (int m = 32; m >= 1; m >>= 1) mx = fmaxf(mx, __shfl_xor(mx, m));
                u *= (1.0f / mx);
                C += __logf(mx);
            }
            sU[lane] = u;                // same-wave LDS ops are in-order
        }

        // log_norm = C + logsumexp(u)
        float mx = u;
#pragma unroll
        for (int m = 32; m >= 1; m >>= 1) mx = fmaxf(mx, __shfl_xor(mx, m));
        float e = u * (1.0f / mx);
#pragma unroll
        for (int m = 32; m >= 1; m >>= 1) e += __shfl_xor(e, m);
        const float log_norm = C + __logf(mx) + __logf(e);

        if (lane == 0)
            atomicAdd(out + (size_t)BB * TT, (log_norm - sc) * (1.0f / BB));
    }
}

extern "C" void kernel_launch(void* const* d_in, const int* in_sizes, int n_in,
                              void* d_out, int out_size, void* d_ws, size_t ws_size,
                              hipStream_t stream) {
    const float* logits = (const float*)d_in[0];
    const int*   nwords = (const int*)d_in[1];
    const int*   tags   = (const int*)d_in[2];
    const float* trans  = (const float*)d_in[3];
    float*       out    = (float*)d_out;

    crf_zero_loss<<<1, 1, 0, stream>>>(out);
    crf_fwd_kernel<<<BB, 128, 0, stream>>>(logits, nwords, tags, trans, out);
}